// Round 1
// baseline (5215.767 us; speedup 1.0000x reference)
//
#include <hip/hip_runtime.h>
#include <math.h>

#define NPTS 8192
#define DIM 32
#define MAX_ITER 10
#define TOL 1e-4f
#define DAMP 0.5f

// ---------------- init: c0 = x, nx[p] = ||x_p||^2 ----------------
__global__ __launch_bounds__(256) void k_init(const float* __restrict__ x,
                                              float* __restrict__ c0,
                                              float* __restrict__ nx) {
    int p = blockIdx.x * blockDim.x + threadIdx.x;
    if (p >= NPTS) return;
    const float4* xr = (const float4*)(x + (size_t)p * DIM);
    float4* cr = (float4*)(c0 + (size_t)p * DIM);
    float s = 0.f;
#pragma unroll
    for (int q = 0; q < 8; ++q) {
        float4 v = xr[q];
        cr[q] = v;
        s += v.x * v.x + v.y * v.y + v.z * v.z + v.w * v.w;
    }
    nx[p] = s;
}

// ---------------- mean-shift step ----------------
// Block: 32 points (rows i), 8 j-slices of 1024. Stage 16 (c_j , x_j) rows
// per slice per round into LDS. new_c[i] = sum_j w_ij x_j / sum_j w_ij,
// w_ij = exp(-(nx_i + nc_j - 2 x_i.c_j) * gamma).
#define MS_SROW 36
__global__ __launch_bounds__(256) void k_ms(const float* __restrict__ x,
                                            const float* __restrict__ nx,
                                            const float* __restrict__ c_cur,
                                            float* __restrict__ c_new,
                                            unsigned int* __restrict__ maxshift,
                                            const float* __restrict__ sigma_p) {
    __shared__ float smem[2 * 8 * 16 * MS_SROW]; // 9216 floats = 36 KB
#define SC_(g, l, cc) smem[(((g)*16 + (l)) * MS_SROW) + (cc)]
#define SX_(g, l, cc) smem[4608 + (((g)*16 + (l)) * MS_SROW) + (cc)]
#define RED_(s, i, dd) smem[(((s)*32 + (i)) * 33) + (dd)]

    int t = threadIdx.x;
    int il = t & 31, sl = t >> 5;
    int bbase = blockIdx.x * 32;
    int i = bbase + il;

    float sg = sigma_p[0];
    float gamma = 1.f / (2.f * sg * sg);

    float xi[DIM];
    const float4* xr = (const float4*)(x + (size_t)i * DIM);
#pragma unroll
    for (int q = 0; q < 8; ++q) {
        float4 v = xr[q];
        xi[4 * q] = v.x; xi[4 * q + 1] = v.y; xi[4 * q + 2] = v.z; xi[4 * q + 3] = v.w;
    }
    float nx_i = nx[i];

    float acc[DIM];
#pragma unroll
    for (int d = 0; d < DIM; ++d) acc[d] = 0.f;
    float wsum = 0.f;

    // staging role
    int q_ = t >> 1, h_ = t & 1;
    int g_ = q_ >> 4, l_ = q_ & 15;

    for (int r = 0; r < 64; ++r) {
        { // stage 8 slices x 16 rows of (c, x); two threads per row
            int j = g_ * 1024 + r * 16 + l_;
            const float4* cr = (const float4*)(c_cur + (size_t)j * DIM) + h_ * 4;
            float pn = 0.f;
            float4* dc = (float4*)&SC_(g_, l_, h_ * 16);
#pragma unroll
            for (int m2 = 0; m2 < 4; ++m2) {
                float4 v = cr[m2];
                dc[m2] = v;
                pn += v.x * v.x + v.y * v.y + v.z * v.z + v.w * v.w;
            }
            SC_(g_, l_, 32 + h_) = pn;
            const float4* xr2 = (const float4*)(x + (size_t)j * DIM) + h_ * 4;
            float4* dx = (float4*)&SX_(g_, l_, h_ * 16);
#pragma unroll
            for (int m2 = 0; m2 < 4; ++m2) dx[m2] = xr2[m2];
        }
        __syncthreads();

        for (int k = 0; k < 16; ++k) {
            float d0 = 0.f, d1 = 0.f, d2 = 0.f, d3 = 0.f;
            float xv[DIM];
#pragma unroll
            for (int q = 0; q < 8; ++q) {
                float4 cv = *(const float4*)&SC_(sl, k, 4 * q);
                float4 xw = *(const float4*)&SX_(sl, k, 4 * q);
                d0 = fmaf(xi[4 * q + 0], cv.x, d0);
                d1 = fmaf(xi[4 * q + 1], cv.y, d1);
                d2 = fmaf(xi[4 * q + 2], cv.z, d2);
                d3 = fmaf(xi[4 * q + 3], cv.w, d3);
                xv[4 * q + 0] = xw.x; xv[4 * q + 1] = xw.y;
                xv[4 * q + 2] = xw.z; xv[4 * q + 3] = xw.w;
            }
            float dot = (d0 + d1) + (d2 + d3);
            float ncj = SC_(sl, k, 32) + SC_(sl, k, 33);
            float sq = fmaxf(nx_i + ncj - 2.f * dot, 0.f);
            float w = __expf(-sq * gamma);
#pragma unroll
            for (int d = 0; d < DIM; ++d) acc[d] = fmaf(w, xv[d], acc[d]);
            wsum += w;
        }
        __syncthreads();
    }

    // reduce 8 slices per point (overlay smem)
#pragma unroll
    for (int d = 0; d < DIM; ++d) RED_(sl, il, d) = acc[d];
    RED_(sl, il, 32) = wsum;
    __syncthreads();

    if (t < 32) {
        int ir = bbase + t;
        float tot[DIM];
#pragma unroll
        for (int d = 0; d < DIM; ++d) tot[d] = 0.f;
        float ws = 0.f;
        for (int s = 0; s < 8; ++s) {
#pragma unroll
            for (int d = 0; d < DIM; ++d) tot[d] += RED_(s, t, d);
            ws += RED_(s, t, 32);
        }
        const float* co = c_cur + (size_t)ir * DIM;
        float sh2 = 0.f;
        float ncv[DIM];
#pragma unroll
        for (int d = 0; d < DIM; ++d) {
            float v = tot[d] / ws;
            ncv[d] = v;
            float df = v - co[d];
            sh2 = fmaf(df, df, sh2);
        }
        float4* dst = (float4*)(c_new + (size_t)ir * DIM);
#pragma unroll
        for (int q = 0; q < 8; ++q)
            dst[q] = make_float4(ncv[4 * q], ncv[4 * q + 1], ncv[4 * q + 2], ncv[4 * q + 3]);
        float sh = sqrtf(sh2);
        atomicMax(maxshift, __float_as_uint(sh));
    }
}

// ---------------- damped update (skipped if converged) ----------------
__global__ __launch_bounds__(256) void k_update(float* __restrict__ c_cur,
                                                const float* __restrict__ c_new,
                                                const unsigned int* __restrict__ maxshift) {
    if (__uint_as_float(*maxshift) < TOL) return;
    int idx = blockIdx.x * blockDim.x + threadIdx.x;
    c_cur[idx] = DAMP * c_cur[idx] + (1.f - DAMP) * c_new[idx];
}

// ---------------- scores: per point argmin over centroids, count ----------------
#define SC2_(g, l, cc) scs[(((g)*32 + (l)) * 36) + (cc)]
__global__ __launch_bounds__(256) void k_scores(const float* __restrict__ x,
                                                const float* __restrict__ nx,
                                                const float* __restrict__ c,
                                                int* __restrict__ scores) {
    __shared__ float scs[8 * 32 * 36];
    __shared__ float mv[8][32];
    __shared__ int mj[8][32];
    int t = threadIdx.x;
    int il = t & 31, sl = t >> 5;
    int p = blockIdx.x * 32 + il;

    float xi[DIM];
    const float4* xr = (const float4*)(x + (size_t)p * DIM);
#pragma unroll
    for (int q = 0; q < 8; ++q) {
        float4 v = xr[q];
        xi[4 * q] = v.x; xi[4 * q + 1] = v.y; xi[4 * q + 2] = v.z; xi[4 * q + 3] = v.w;
    }
    float nxp = nx[p];

    float bestv = INFINITY;
    int bestj = 0;

    for (int r = 0; r < 32; ++r) {
        { // each thread stages one centroid row + its norm
            int j = sl * 1024 + r * 32 + il;
            const float4* cr = (const float4*)(c + (size_t)j * DIM);
            float nc = 0.f;
            float4* dc = (float4*)&SC2_(sl, il, 0);
#pragma unroll
            for (int q = 0; q < 8; ++q) {
                float4 v = cr[q];
                dc[q] = v;
                nc += v.x * v.x + v.y * v.y + v.z * v.z + v.w * v.w;
            }
            SC2_(sl, il, 32) = nc;
        }
        __syncthreads();
        for (int k = 0; k < 32; ++k) {
            float d0 = 0.f, d1 = 0.f, d2 = 0.f, d3 = 0.f;
#pragma unroll
            for (int q = 0; q < 8; ++q) {
                float4 v = *(const float4*)&SC2_(sl, k, 4 * q);
                d0 = fmaf(xi[4 * q + 0], v.x, d0);
                d1 = fmaf(xi[4 * q + 1], v.y, d1);
                d2 = fmaf(xi[4 * q + 2], v.z, d2);
                d3 = fmaf(xi[4 * q + 3], v.w, d3);
            }
            float dot = (d0 + d1) + (d2 + d3);
            float sq = fmaxf(nxp + SC2_(sl, k, 32) - 2.f * dot, 0.f);
            int j2 = sl * 1024 + r * 32 + k;
            if (sq < bestv) { bestv = sq; bestj = j2; } // strict < : first min wins
        }
        __syncthreads();
    }
    mv[sl][il] = bestv;
    mj[sl][il] = bestj;
    __syncthreads();
    if (t < 32) {
        float bv = mv[0][t];
        int bj = mj[0][t];
        for (int s = 1; s < 8; ++s) {
            if (mv[s][t] < bv) { bv = mv[s][t]; bj = mj[s][t]; } // slices ascend in j
        }
        atomicAdd(&scores[bj], 1);
    }
}

// ---------------- stable descending rank -> order ----------------
__global__ __launch_bounds__(256) void k_rank(const int* __restrict__ scores,
                                              int* __restrict__ order) {
    __shared__ int s_sc[NPTS];
    int t = threadIdx.x;
    for (int q = t; q < NPTS; q += 256) s_sc[q] = scores[q];
    __syncthreads();
    int i = blockIdx.x * 256 + t;
    int si = s_sc[i];
    int r = 0;
    for (int j = 0; j < NPTS; ++j) {
        int sj = s_sc[j];
        r += (sj > si) || (sj == si && j < i);
    }
    order[r] = i;
}

// ---------------- greedy NMS scan (ballot fast-forward) ----------------
__global__ __launch_bounds__(1024) void k_nms(const float* __restrict__ c,
                                              const int* __restrict__ order,
                                              const int* __restrict__ scores,
                                              const float* __restrict__ sigma_p,
                                              float* __restrict__ keep_out) {
    __shared__ int s_ord[NPTS];
    __shared__ unsigned char kp[NPTS];
    __shared__ int s_first[16];
    __shared__ int s_next;
    int t = threadIdx.x;
    for (int q = t; q < NPTS; q += 1024) { s_ord[q] = order[q]; kp[q] = 1; }
    __syncthreads();
    float sg = sigma_p[0];
    float thr2 = sg * sg;

    int k = 0;
    while (k < NPTS) {
        int cand = k + t;
        bool hit = (cand < NPTS) && (kp[s_ord[cand]] != 0);
        unsigned long long b = __ballot(hit);
        int wave = t >> 6;
        if ((t & 63) == 0)
            s_first[wave] = b ? (k + (wave << 6) + (__ffsll((unsigned long long)b) - 1))
                              : 0x7fffffff;
        __syncthreads();
        if (t == 0) {
            int mn = s_first[0];
            for (int w2 = 1; w2 < 16; ++w2) mn = min(mn, s_first[w2]);
            s_next = mn;
        }
        __syncthreads();
        int kf = s_next;
        if (kf == 0x7fffffff) { k += 1024; continue; }

        int idx = s_ord[kf];
        float ci[DIM];
        const float4* cr = (const float4*)(c + (size_t)idx * DIM);
#pragma unroll
        for (int q = 0; q < 8; ++q) {
            float4 v = cr[q];
            ci[4 * q] = v.x; ci[4 * q + 1] = v.y; ci[4 * q + 2] = v.z; ci[4 * q + 3] = v.w;
        }
#pragma unroll
        for (int m2 = 0; m2 < 8; ++m2) {
            int j = t + m2 * 1024;
            const float4* cj = (const float4*)(c + (size_t)j * DIM);
            float sq = 0.f;
#pragma unroll
            for (int q = 0; q < 8; ++q) {
                float4 v = cj[q];
                float e0 = v.x - ci[4 * q], e1 = v.y - ci[4 * q + 1];
                float e2 = v.z - ci[4 * q + 2], e3 = v.w - ci[4 * q + 3];
                sq += e0 * e0 + e1 * e1 + e2 * e2 + e3 * e3;
            }
            if (j != idx && sq < thr2) kp[j] = 0;
        }
        __syncthreads();
        if (t == 0) kp[idx] = (scores[idx] > 0) ? 1 : 0;
        __syncthreads();
        k = kf + 1;
    }
    __syncthreads();
    for (int q = t; q < NPTS; q += 1024) keep_out[q] = kp[q] ? 1.0f : 0.0f;
}

// ---------------- assignment softmax over kept centroids ----------------
__global__ __launch_bounds__(256) void k_assign(const float* __restrict__ x,
                                                const float* __restrict__ c,
                                                const float* __restrict__ keepf,
                                                float* __restrict__ A) {
    __shared__ float scs[8 * 32 * 36]; // [32]=nc, [33]=keep
    __shared__ float mvv[8][32];
    __shared__ float svv[8][32];
    __shared__ float bM[32], bI[32];
    int t = threadIdx.x;
    int il = t & 31, sl = t >> 5;
    int p = blockIdx.x * 32 + il;

    float xi[DIM];
    float nxp = 0.f;
    const float4* xr = (const float4*)(x + (size_t)p * DIM);
#pragma unroll
    for (int q = 0; q < 8; ++q) {
        float4 v = xr[q];
        xi[4 * q] = v.x; xi[4 * q + 1] = v.y; xi[4 * q + 2] = v.z; xi[4 * q + 3] = v.w;
        nxp += v.x * v.x + v.y * v.y + v.z * v.z + v.w * v.w; // same order as k_init
    }

    float m = -INFINITY, S = 0.f;

    for (int r = 0; r < 32; ++r) {
        {
            int j = sl * 1024 + r * 32 + il;
            const float4* cr = (const float4*)(c + (size_t)j * DIM);
            float nc = 0.f;
            float4* dc = (float4*)&SC2_(sl, il, 0);
#pragma unroll
            for (int q = 0; q < 8; ++q) {
                float4 v = cr[q];
                dc[q] = v;
                nc += v.x * v.x + v.y * v.y + v.z * v.z + v.w * v.w;
            }
            SC2_(sl, il, 32) = nc;
            SC2_(sl, il, 33) = keepf[j];
        }
        __syncthreads();
        for (int k = 0; k < 32; ++k) {
            float d0 = 0.f, d1 = 0.f, d2 = 0.f, d3 = 0.f;
#pragma unroll
            for (int q = 0; q < 8; ++q) {
                float4 v = *(const float4*)&SC2_(sl, k, 4 * q);
                d0 = fmaf(xi[4 * q + 0], v.x, d0);
                d1 = fmaf(xi[4 * q + 1], v.y, d1);
                d2 = fmaf(xi[4 * q + 2], v.z, d2);
                d3 = fmaf(xi[4 * q + 3], v.w, d3);
            }
            float dot = (d0 + d1) + (d2 + d3);
            float sq = fmaxf(nxp + SC2_(sl, k, 32) - 2.f * dot, 0.f);
            float cost = -sqrtf(sq + 1e-12f);
            if (SC2_(sl, k, 33) > 0.5f) {
                if (cost > m) {
                    S = S * __expf(m - cost) + 1.f;
                    m = cost;
                } else {
                    S += __expf(cost - m);
                }
            }
        }
        __syncthreads();
    }

    mvv[sl][il] = m;
    svv[sl][il] = S;
    __syncthreads();
    if (t < 32) {
        float M = mvv[0][t];
        for (int s = 1; s < 8; ++s) M = fmaxf(M, mvv[s][t]);
        float SS = 0.f;
        for (int s = 0; s < 8; ++s) SS += svv[s][t] * __expf(mvv[s][t] - M);
        bM[t] = M;
        bI[t] = 1.f / SS;
    }
    __syncthreads();
    float M = bM[il], inv = bI[il];

    // pass 2: recompute and write normalized probabilities
    for (int r = 0; r < 32; ++r) {
        {
            int j = sl * 1024 + r * 32 + il;
            const float4* cr = (const float4*)(c + (size_t)j * DIM);
            float nc = 0.f;
            float4* dc = (float4*)&SC2_(sl, il, 0);
#pragma unroll
            for (int q = 0; q < 8; ++q) {
                float4 v = cr[q];
                dc[q] = v;
                nc += v.x * v.x + v.y * v.y + v.z * v.z + v.w * v.w;
            }
            SC2_(sl, il, 32) = nc;
            SC2_(sl, il, 33) = keepf[j];
        }
        __syncthreads();
        for (int k4 = 0; k4 < 8; ++k4) {
            float vals[4];
#pragma unroll
            for (int u = 0; u < 4; ++u) {
                int k = k4 * 4 + u;
                float d0 = 0.f, d1 = 0.f, d2 = 0.f, d3 = 0.f;
#pragma unroll
                for (int q = 0; q < 8; ++q) {
                    float4 v = *(const float4*)&SC2_(sl, k, 4 * q);
                    d0 = fmaf(xi[4 * q + 0], v.x, d0);
                    d1 = fmaf(xi[4 * q + 1], v.y, d1);
                    d2 = fmaf(xi[4 * q + 2], v.z, d2);
                    d3 = fmaf(xi[4 * q + 3], v.w, d3);
                }
                float dot = (d0 + d1) + (d2 + d3);
                float sq = fmaxf(nxp + SC2_(sl, k, 32) - 2.f * dot, 0.f);
                float cost = -sqrtf(sq + 1e-12f);
                vals[u] = (SC2_(sl, k, 33) > 0.5f) ? __expf(cost - M) * inv : 0.f;
            }
            *(float4*)(A + (size_t)p * NPTS + sl * 1024 + r * 32 + k4 * 4) =
                make_float4(vals[0], vals[1], vals[2], vals[3]);
        }
        __syncthreads();
    }
}

extern "C" void kernel_launch(void* const* d_in, const int* in_sizes, int n_in,
                              void* d_out, int out_size, void* d_ws, size_t ws_size,
                              hipStream_t stream) {
    const float* x = (const float*)d_in[0];
    const float* sigma = (const float*)d_in[1];

    float* out = (float*)d_out;
    float* OUT_C = out;                            // NPTS*DIM
    float* OUT_A = out + (size_t)NPTS * DIM;       // NPTS*NPTS
    float* OUT_K = OUT_A + (size_t)NPTS * NPTS;    // NPTS

    // scratch inside the assignment region (fully consumed before k_assign)
    float* c_cur = OUT_A;
    float* c_new = OUT_A + NPTS * DIM;
    float* nx = OUT_A + 2 * NPTS * DIM;
    unsigned int* maxshift = (unsigned int*)(nx + NPTS);
    int* scores = (int*)(nx + NPTS + 64);
    int* order = scores + NPTS;

    k_init<<<NPTS / 256, 256, 0, stream>>>(x, c_cur, nx);
    for (int it = 0; it < MAX_ITER; ++it) {
        hipMemsetAsync(maxshift, 0, sizeof(unsigned int), stream);
        k_ms<<<256, 256, 0, stream>>>(x, nx, c_cur, c_new, maxshift, sigma);
        k_update<<<(NPTS * DIM) / 256, 256, 0, stream>>>(c_cur, c_new, maxshift);
    }
    hipMemcpyAsync(OUT_C, c_cur, (size_t)NPTS * DIM * sizeof(float),
                   hipMemcpyDeviceToDevice, stream);
    hipMemsetAsync(scores, 0, NPTS * sizeof(int), stream);
    k_scores<<<NPTS / 32, 256, 0, stream>>>(x, nx, OUT_C, scores);
    k_rank<<<NPTS / 256, 256, 0, stream>>>(scores, order);
    k_nms<<<1, 1024, 0, stream>>>(OUT_C, order, scores, sigma, OUT_K);
    k_assign<<<NPTS / 32, 256, 0, stream>>>(x, OUT_C, OUT_K, OUT_A);
}

// Round 2
// 1887.880 us; speedup vs baseline: 2.7628x; 2.7628x over previous
//
#include <hip/hip_runtime.h>
#include <math.h>

#define NPTS 8192
#define DIM 32
#define MAX_ITER 10
#define TOL 1e-4f
#define DAMP 0.5f

// ---- scratch layout inside OUT_A (floats from A base) ----
#define OFF_MSP   0u                     // 32*33*8192 mean-shift partials
#define OFF_CCUR  8650752u               // 8192*32
#define OFF_CNEW  8912896u               // 8192*32
#define OFF_NX    9175040u               // 8192
#define OFF_NC    9183232u               // 8192
#define OFF_PV    9191424u               // 32*8192 argmin partial val
#define OFF_PJ    9453568u               // 32*8192 argmin partial idx (int)
#define OFF_RKP   9715712u               // 32*8192 rank partials (int)
#define OFF_PM    9977856u               // 32*8192 softmax partial max
#define OFF_PS   10240000u               // 32*8192 softmax partial sum
#define OFF_MSH  10502144u               // maxshift (uint)
#define OFF_SCO  10502208u               // 8192 scores (int)
#define OFF_ORD  10510400u               // 8192 order (int)

// ---------------- init: c0 = x, nx = nc = ||x||^2 ----------------
__global__ __launch_bounds__(256) void k_init(const float* __restrict__ x,
                                              float* __restrict__ c0,
                                              float* __restrict__ nx,
                                              float* __restrict__ nc) {
    int p = blockIdx.x * blockDim.x + threadIdx.x;
    const float4* xr = (const float4*)(x + (size_t)p * DIM);
    float4* cr = (float4*)(c0 + (size_t)p * DIM);
    float s = 0.f;
#pragma unroll
    for (int q = 0; q < 8; ++q) {
        float4 v = xr[q];
        cr[q] = v;
        s += v.x * v.x + v.y * v.y + v.z * v.z + v.w * v.w;
    }
    nx[p] = s;
    nc[p] = s;
}

// ---------------- mean-shift partial pass (uniform-j, SGPR stream) ----------------
// grid 1024 = 32 i-tiles x 32 j-splits; 256 thr = 4 indep waves; lane owns one i.
__global__ __launch_bounds__(256) void k_ms2(const float* __restrict__ x,
                                             const float* __restrict__ nx,
                                             const float* __restrict__ c,
                                             const float* __restrict__ nc,
                                             const float* __restrict__ sigma_p,
                                             float* __restrict__ P) {
    int t = threadIdx.x;
    int wv = __builtin_amdgcn_readfirstlane(t >> 6);
    int lane = t & 63;
    int it = (int)blockIdx.x >> 5, js = (int)blockIdx.x & 31;
    int i = it * 256 + wv * 64 + lane;

    float sg = sigma_p[0];
    float gamma = 1.f / (2.f * sg * sg);

    float xi[DIM];
    const float4* xr = (const float4*)(x + (size_t)i * DIM);
#pragma unroll
    for (int q = 0; q < 8; ++q) {
        float4 v = xr[q];
        xi[4 * q] = v.x; xi[4 * q + 1] = v.y; xi[4 * q + 2] = v.z; xi[4 * q + 3] = v.w;
    }
    float nxi = nx[i];

    float acc[DIM];
#pragma unroll
    for (int d = 0; d < DIM; ++d) acc[d] = 0.f;
    float wsum = 0.f;

    int j0 = js * 256;
    const float* cb = c + (size_t)j0 * DIM;
    const float* xb = x + (size_t)j0 * DIM;
    const float* ncb = nc + j0;

    for (int jj = 0; jj < 256; ++jj) {
        const float4* cr = (const float4*)(cb + (size_t)jj * DIM);
        const float4* xr2 = (const float4*)(xb + (size_t)jj * DIM);
        float4 C[8], X[8];
#pragma unroll
        for (int q = 0; q < 8; ++q) C[q] = cr[q];
#pragma unroll
        for (int q = 0; q < 8; ++q) X[q] = xr2[q];
        float ncj = ncb[jj];
        float d0 = 0.f, d1 = 0.f, d2 = 0.f, d3 = 0.f;
#pragma unroll
        for (int q = 0; q < 8; ++q) {
            d0 = fmaf(xi[4 * q + 0], C[q].x, d0);
            d1 = fmaf(xi[4 * q + 1], C[q].y, d1);
            d2 = fmaf(xi[4 * q + 2], C[q].z, d2);
            d3 = fmaf(xi[4 * q + 3], C[q].w, d3);
        }
        float sq = fmaxf(nxi + ncj - 2.f * ((d0 + d1) + (d2 + d3)), 0.f);
        float w = __expf(-sq * gamma);
        wsum += w;
#pragma unroll
        for (int q = 0; q < 8; ++q) {
            acc[4 * q + 0] = fmaf(w, X[q].x, acc[4 * q + 0]);
            acc[4 * q + 1] = fmaf(w, X[q].y, acc[4 * q + 1]);
            acc[4 * q + 2] = fmaf(w, X[q].z, acc[4 * q + 2]);
            acc[4 * q + 3] = fmaf(w, X[q].w, acc[4 * q + 3]);
        }
    }

    size_t base = ((size_t)js * 33) * NPTS + i;
#pragma unroll
    for (int d = 0; d < DIM; ++d) P[base + (size_t)d * NPTS] = acc[d];
    P[base + (size_t)32 * NPTS] = wsum;
}

// ---------------- reduce partials -> c_new, maxshift ----------------
__global__ __launch_bounds__(256) void k_reduce(const float* __restrict__ P,
                                                const float* __restrict__ c_cur,
                                                float* __restrict__ c_new,
                                                unsigned int* __restrict__ maxshift) {
    int i = blockIdx.x * 256 + threadIdx.x;
    float tot[33];
#pragma unroll
    for (int d = 0; d < 33; ++d) tot[d] = 0.f;
    for (int js = 0; js < 32; ++js) {
        size_t base = ((size_t)js * 33) * NPTS + i;
#pragma unroll
        for (int d = 0; d < 33; ++d) tot[d] += P[base + (size_t)d * NPTS];
    }
    float ws = tot[32];
    const float* co = c_cur + (size_t)i * DIM;
    float sh2 = 0.f;
    float ncv[DIM];
#pragma unroll
    for (int d = 0; d < DIM; ++d) {
        float v = tot[d] / ws;
        ncv[d] = v;
        float df = v - co[d];
        sh2 = fmaf(df, df, sh2);
    }
    float4* dst = (float4*)(c_new + (size_t)i * DIM);
#pragma unroll
    for (int q = 0; q < 8; ++q)
        dst[q] = make_float4(ncv[4 * q], ncv[4 * q + 1], ncv[4 * q + 2], ncv[4 * q + 3]);
    atomicMax(maxshift, __float_as_uint(sqrtf(sh2)));
}

// ---------------- damped update + nc refresh (skipped when converged) ----------------
__global__ __launch_bounds__(256) void k_update(float* __restrict__ c_cur,
                                                const float* __restrict__ c_new,
                                                float* __restrict__ nc,
                                                const unsigned int* __restrict__ maxshift) {
    if (__uint_as_float(*maxshift) < TOL) return;
    int i = blockIdx.x * 256 + threadIdx.x;
    float4* cc = (float4*)(c_cur + (size_t)i * DIM);
    const float4* cn = (const float4*)(c_new + (size_t)i * DIM);
    float s = 0.f;
#pragma unroll
    for (int q = 0; q < 8; ++q) {
        float4 a = cc[q], b = cn[q];
        float4 r = make_float4(DAMP * a.x + (1.f - DAMP) * b.x,
                               DAMP * a.y + (1.f - DAMP) * b.y,
                               DAMP * a.z + (1.f - DAMP) * b.z,
                               DAMP * a.w + (1.f - DAMP) * b.w);
        cc[q] = r;
        s += r.x * r.x + r.y * r.y + r.z * r.z + r.w * r.w;
    }
    nc[i] = s;
}

// ---------------- scores: partial argmin per (p, j-split) ----------------
__global__ __launch_bounds__(256) void k_scores2(const float* __restrict__ x,
                                                 const float* __restrict__ nx,
                                                 const float* __restrict__ c,
                                                 const float* __restrict__ nc,
                                                 float* __restrict__ pv,
                                                 int* __restrict__ pj) {
    int t = threadIdx.x;
    int wv = __builtin_amdgcn_readfirstlane(t >> 6);
    int lane = t & 63;
    int it = (int)blockIdx.x >> 5, js = (int)blockIdx.x & 31;
    int p = it * 256 + wv * 64 + lane;

    float xi[DIM];
    const float4* xr = (const float4*)(x + (size_t)p * DIM);
#pragma unroll
    for (int q = 0; q < 8; ++q) {
        float4 v = xr[q];
        xi[4 * q] = v.x; xi[4 * q + 1] = v.y; xi[4 * q + 2] = v.z; xi[4 * q + 3] = v.w;
    }
    float nxp = nx[p];

    int j0 = js * 256;
    const float* cb = c + (size_t)j0 * DIM;
    const float* ncb = nc + j0;
    float bestv = INFINITY;
    int bestj = j0;
    for (int jj = 0; jj < 256; ++jj) {
        const float4* cr = (const float4*)(cb + (size_t)jj * DIM);
        float4 C[8];
#pragma unroll
        for (int q = 0; q < 8; ++q) C[q] = cr[q];
        float d0 = 0.f, d1 = 0.f, d2 = 0.f, d3 = 0.f;
#pragma unroll
        for (int q = 0; q < 8; ++q) {
            d0 = fmaf(xi[4 * q + 0], C[q].x, d0);
            d1 = fmaf(xi[4 * q + 1], C[q].y, d1);
            d2 = fmaf(xi[4 * q + 2], C[q].z, d2);
            d3 = fmaf(xi[4 * q + 3], C[q].w, d3);
        }
        float sq = fmaxf(nxp + ncb[jj] - 2.f * ((d0 + d1) + (d2 + d3)), 0.f);
        if (sq < bestv) { bestv = sq; bestj = j0 + jj; }  // strict <: first min
    }
    pv[(size_t)js * NPTS + p] = bestv;
    pj[(size_t)js * NPTS + p] = bestj;
}

__global__ __launch_bounds__(256) void k_score_comb(const float* __restrict__ pv,
                                                    const int* __restrict__ pj,
                                                    int* __restrict__ scores) {
    int p = blockIdx.x * 256 + threadIdx.x;
    float bv = pv[p];
    int bj = pj[p];
    for (int js = 1; js < 32; ++js) {
        float v = pv[(size_t)js * NPTS + p];
        int j = pj[(size_t)js * NPTS + p];
        if (v < bv) { bv = v; bj = j; }  // ascending js: first global min
    }
    atomicAdd(&scores[bj], 1);
}

// ---------------- stable descending rank (split + combine) ----------------
__global__ __launch_bounds__(256) void k_rank_part(const int* __restrict__ scores,
                                                   int* __restrict__ rkp) {
    int t = threadIdx.x;
    int wv = __builtin_amdgcn_readfirstlane(t >> 6);
    int lane = t & 63;
    int it = (int)blockIdx.x >> 5, js = (int)blockIdx.x & 31;
    int p = it * 256 + wv * 64 + lane;
    int sp = scores[p];
    int j0 = js * 256;
    int r = 0;
    for (int jj = 0; jj < 256; ++jj) {
        int sj = scores[j0 + jj];
        int j = j0 + jj;
        r += (sj > sp) || (sj == sp && j < p);
    }
    rkp[(size_t)js * NPTS + p] = r;
}

__global__ __launch_bounds__(256) void k_rank_comb(const int* __restrict__ rkp,
                                                   int* __restrict__ order) {
    int p = blockIdx.x * 256 + threadIdx.x;
    int r = 0;
    for (int js = 0; js < 32; ++js) r += rkp[(size_t)js * NPTS + p];
    order[r] = p;
}

// ---------------- greedy NMS scan (single block, ballot fast-forward) ----------------
__global__ __launch_bounds__(1024) void k_nms(const float* __restrict__ c,
                                              const int* __restrict__ order,
                                              const int* __restrict__ scores,
                                              const float* __restrict__ sigma_p,
                                              float* __restrict__ keep_out) {
    __shared__ int s_ord[NPTS];
    __shared__ unsigned char kp[NPTS];
    __shared__ int s_first[16];
    __shared__ int s_next;
    int t = threadIdx.x;
    for (int q = t; q < NPTS; q += 1024) { s_ord[q] = order[q]; kp[q] = 1; }
    __syncthreads();
    float sg = sigma_p[0];
    float thr2 = sg * sg;

    int k = 0;
    while (k < NPTS) {
        int cand = k + t;
        bool hit = (cand < NPTS) && (kp[s_ord[cand]] != 0);
        unsigned long long b = __ballot(hit);
        int wave = t >> 6;
        if ((t & 63) == 0)
            s_first[wave] = b ? (k + (wave << 6) + (__ffsll((unsigned long long)b) - 1))
                              : 0x7fffffff;
        __syncthreads();
        if (t == 0) {
            int mn = s_first[0];
            for (int w2 = 1; w2 < 16; ++w2) mn = min(mn, s_first[w2]);
            s_next = mn;
        }
        __syncthreads();
        int kf = s_next;
        if (kf == 0x7fffffff) { k += 1024; continue; }

        int idx = s_ord[kf];
        float ci[DIM];
        const float4* cr = (const float4*)(c + (size_t)idx * DIM);
#pragma unroll
        for (int q = 0; q < 8; ++q) {
            float4 v = cr[q];
            ci[4 * q] = v.x; ci[4 * q + 1] = v.y; ci[4 * q + 2] = v.z; ci[4 * q + 3] = v.w;
        }
#pragma unroll
        for (int m2 = 0; m2 < 8; ++m2) {
            int j = t + m2 * 1024;
            const float4* cj = (const float4*)(c + (size_t)j * DIM);
            float sq = 0.f;
#pragma unroll
            for (int q = 0; q < 8; ++q) {
                float4 v = cj[q];
                float e0 = v.x - ci[4 * q], e1 = v.y - ci[4 * q + 1];
                float e2 = v.z - ci[4 * q + 2], e3 = v.w - ci[4 * q + 3];
                sq += e0 * e0 + e1 * e1 + e2 * e2 + e3 * e3;
            }
            if (j != idx && sq < thr2) kp[j] = 0;
        }
        __syncthreads();
        if (t == 0) kp[idx] = (scores[idx] > 0) ? 1 : 0;
        __syncthreads();
        k = kf + 1;
    }
    __syncthreads();
    for (int q = t; q < NPTS; q += 1024) keep_out[q] = kp[q] ? 1.0f : 0.0f;
}

// ---------------- assignment pass 1: partial (max, sum) per (p, j-split) ----------------
__global__ __launch_bounds__(256) void k_apass1(const float* __restrict__ x,
                                                const float* __restrict__ nx,
                                                const float* __restrict__ c,
                                                const float* __restrict__ nc,
                                                const float* __restrict__ keepf,
                                                float* __restrict__ pm,
                                                float* __restrict__ ps) {
    int t = threadIdx.x;
    int wv = __builtin_amdgcn_readfirstlane(t >> 6);
    int lane = t & 63;
    int it = (int)blockIdx.x >> 5, js = (int)blockIdx.x & 31;
    int p = it * 256 + wv * 64 + lane;

    float xi[DIM];
    const float4* xr = (const float4*)(x + (size_t)p * DIM);
#pragma unroll
    for (int q = 0; q < 8; ++q) {
        float4 v = xr[q];
        xi[4 * q] = v.x; xi[4 * q + 1] = v.y; xi[4 * q + 2] = v.z; xi[4 * q + 3] = v.w;
    }
    float nxp = nx[p];

    int j0 = js * 256;
    const float* cb = c + (size_t)j0 * DIM;
    const float* ncb = nc + j0;
    const float* kb = keepf + j0;
    float m = -1e30f, S = 0.f;
    for (int jj = 0; jj < 256; ++jj) {
        const float4* cr = (const float4*)(cb + (size_t)jj * DIM);
        float4 C[8];
#pragma unroll
        for (int q = 0; q < 8; ++q) C[q] = cr[q];
        float d0 = 0.f, d1 = 0.f, d2 = 0.f, d3 = 0.f;
#pragma unroll
        for (int q = 0; q < 8; ++q) {
            d0 = fmaf(xi[4 * q + 0], C[q].x, d0);
            d1 = fmaf(xi[4 * q + 1], C[q].y, d1);
            d2 = fmaf(xi[4 * q + 2], C[q].z, d2);
            d3 = fmaf(xi[4 * q + 3], C[q].w, d3);
        }
        float sq = fmaxf(nxp + ncb[jj] - 2.f * ((d0 + d1) + (d2 + d3)), 0.f);
        float cost = -sqrtf(sq + 1e-12f);
        float ck = (kb[jj] > 0.5f) ? cost : -INFINITY;
        float mn = fmaxf(m, ck);
        S = S * __expf(m - mn) + __expf(ck - mn);
        m = mn;
    }
    pm[(size_t)js * NPTS + p] = m;
    ps[(size_t)js * NPTS + p] = S;
}

// ---------------- assignment combine: stash M, 1/SS, nx into row tail ----------------
__global__ __launch_bounds__(256) void k_acomb(const float* __restrict__ pm,
                                               const float* __restrict__ ps,
                                               const float* __restrict__ nx,
                                               float* __restrict__ A) {
    int p = blockIdx.x * 256 + threadIdx.x;
    float M = -1e30f;
    for (int js = 0; js < 32; ++js) M = fmaxf(M, pm[(size_t)js * NPTS + p]);
    float SS = 0.f;
    for (int js = 0; js < 32; ++js)
        SS += ps[(size_t)js * NPTS + p] * __expf(pm[(size_t)js * NPTS + p] - M);
    float* row = A + (size_t)p * NPTS;
    row[8189] = nx[p];
    row[8190] = M;
    row[8191] = 1.f / SS;
}

// ---------------- assignment pass 2: write probabilities ----------------
// block owns 16 rows; per-row (nx, M, inv) cached in LDS before any write.
// waves own interleaved j-chunks (64 wide); c-chunk lives in VGPRs.
__global__ __launch_bounds__(256) void k_apass2(const float* __restrict__ x,
                                                const float* __restrict__ c,
                                                const float* __restrict__ keepf,
                                                float* __restrict__ A) {
    __shared__ float sNX[16], sM[16], sI[16];
    int t = threadIdx.x;
    int wv = __builtin_amdgcn_readfirstlane(t >> 6);
    int lane = t & 63;
    int p0 = blockIdx.x * 16;
    if (t < 16) {
        const float* row = A + (size_t)(p0 + t) * NPTS;
        sNX[t] = row[8189];
        sM[t] = row[8190];
        sI[t] = row[8191];
    }
    __syncthreads();

    for (int ch = wv; ch < 128; ch += 4) {  // ascending: stash cols (ch=127) last
        int j = ch * 64 + lane;
        float cj[DIM];
        const float4* cr = (const float4*)(c + (size_t)j * DIM);
        float ncj = 0.f;
#pragma unroll
        for (int q = 0; q < 8; ++q) {
            float4 v = cr[q];
            cj[4 * q] = v.x; cj[4 * q + 1] = v.y; cj[4 * q + 2] = v.z; cj[4 * q + 3] = v.w;
            ncj += v.x * v.x + v.y * v.y + v.z * v.z + v.w * v.w;
        }
        float kpj = keepf[j];
        for (int pp = 0; pp < 16; ++pp) {
            const float4* xrow = (const float4*)(x + (size_t)(p0 + pp) * DIM);  // uniform
            float4 X[8];
#pragma unroll
            for (int q = 0; q < 8; ++q) X[q] = xrow[q];
            float nxp = sNX[pp], M = sM[pp], inv = sI[pp];
            float d0 = 0.f, d1 = 0.f, d2 = 0.f, d3 = 0.f;
#pragma unroll
            for (int q = 0; q < 8; ++q) {
                d0 = fmaf(cj[4 * q + 0], X[q].x, d0);
                d1 = fmaf(cj[4 * q + 1], X[q].y, d1);
                d2 = fmaf(cj[4 * q + 2], X[q].z, d2);
                d3 = fmaf(cj[4 * q + 3], X[q].w, d3);
            }
            float sq = fmaxf(nxp + ncj - 2.f * ((d0 + d1) + (d2 + d3)), 0.f);
            float cost = -sqrtf(sq + 1e-12f);
            float v = (kpj > 0.5f) ? __expf(cost - M) * inv : 0.f;
            A[(size_t)(p0 + pp) * NPTS + j] = v;
        }
    }
}

extern "C" void kernel_launch(void* const* d_in, const int* in_sizes, int n_in,
                              void* d_out, int out_size, void* d_ws, size_t ws_size,
                              hipStream_t stream) {
    const float* x = (const float*)d_in[0];
    const float* sigma = (const float*)d_in[1];

    float* out = (float*)d_out;
    float* OUT_C = out;                          // NPTS*DIM
    float* A = out + (size_t)NPTS * DIM;         // NPTS*NPTS
    float* OUT_K = A + (size_t)NPTS * NPTS;      // NPTS

    float* msP = A + OFF_MSP;
    float* c_cur = A + OFF_CCUR;
    float* c_new = A + OFF_CNEW;
    float* nx = A + OFF_NX;
    float* nc = A + OFF_NC;
    float* pv = A + OFF_PV;
    int* pj = (int*)(A + OFF_PJ);
    int* rkp = (int*)(A + OFF_RKP);
    float* pm = A + OFF_PM;
    float* ps = A + OFF_PS;
    unsigned int* maxshift = (unsigned int*)(A + OFF_MSH);
    int* scores = (int*)(A + OFF_SCO);
    int* order = (int*)(A + OFF_ORD);

    k_init<<<NPTS / 256, 256, 0, stream>>>(x, c_cur, nx, nc);
    for (int itr = 0; itr < MAX_ITER; ++itr) {
        hipMemsetAsync(maxshift, 0, sizeof(unsigned int), stream);
        k_ms2<<<1024, 256, 0, stream>>>(x, nx, c_cur, nc, sigma, msP);
        k_reduce<<<NPTS / 256, 256, 0, stream>>>(msP, c_cur, c_new, maxshift);
        k_update<<<NPTS / 256, 256, 0, stream>>>(c_cur, c_new, nc, maxshift);
    }
    hipMemcpyAsync(OUT_C, c_cur, (size_t)NPTS * DIM * sizeof(float),
                   hipMemcpyDeviceToDevice, stream);

    hipMemsetAsync(scores, 0, NPTS * sizeof(int), stream);
    k_scores2<<<1024, 256, 0, stream>>>(x, nx, OUT_C, nc, pv, pj);
    k_score_comb<<<NPTS / 256, 256, 0, stream>>>(pv, pj, scores);
    k_rank_part<<<1024, 256, 0, stream>>>(scores, rkp);
    k_rank_comb<<<NPTS / 256, 256, 0, stream>>>(rkp, order);
    k_nms<<<1, 1024, 0, stream>>>(OUT_C, order, scores, sigma, OUT_K);

    k_apass1<<<1024, 256, 0, stream>>>(x, nx, OUT_C, nc, OUT_K, pm, ps);
    k_acomb<<<NPTS / 256, 256, 0, stream>>>(pm, ps, nx, A);
    k_apass2<<<NPTS / 16, 256, 0, stream>>>(x, OUT_C, OUT_K, A);
}

// Round 3
// 1822.463 us; speedup vs baseline: 2.8619x; 1.0359x over previous
//
#include <hip/hip_runtime.h>
#include <math.h>

#define NPTS 8192
#define DIM 32
#define MAX_ITER 10
#define TOL 1e-4f
#define DAMP 0.5f
#define LOG2E 1.4426950408889634f

// ---- scratch layout inside OUT_A (floats from A base); all consumed before k_apass2 ----
#define OFF_MSP   0u          // 32*33*8192 mean-shift partials
#define OFF_CCUR  8650752u    // 8192*32
#define OFF_CNEW  8912896u    // 8192*32
#define OFF_NX    9175040u    // 8192
#define OFF_NC    9183232u    // 8192
#define OFF_PV    9191424u    // 32*8192 argmin partial val
#define OFF_PJ    9453568u    // 32*8192 argmin partial idx (int)
#define OFF_RKP   9715712u    // 32*8192 rank partials (int)
#define OFF_MSH   9977856u    // 16 maxshift slots (uint)
#define OFF_SCO   9977872u    // 8192 scores (int)
#define OFF_ORD   9986064u    // 8192 order (int)
// d_ws: ps softmax-sum partials, 32*8192 floats = 1 MB (must survive apass2's A writes)

// ---------------- init: c0 = x, nx = nc = ||x||^2; zero scores & maxshift ----------------
__global__ __launch_bounds__(256) void k_init(const float* __restrict__ x,
                                              float* __restrict__ c0,
                                              float* __restrict__ nx,
                                              float* __restrict__ nc,
                                              int* __restrict__ scores,
                                              unsigned int* __restrict__ msh) {
    int p = blockIdx.x * blockDim.x + threadIdx.x;
    const float4* xr = (const float4*)(x + (size_t)p * DIM);
    float4* cr = (float4*)(c0 + (size_t)p * DIM);
    float s = 0.f;
#pragma unroll
    for (int q = 0; q < 8; ++q) {
        float4 v = xr[q];
        cr[q] = v;
        s += v.x * v.x + v.y * v.y + v.z * v.z + v.w * v.w;
    }
    nx[p] = s;
    nc[p] = s;
    scores[p] = 0;
    if (blockIdx.x == 0 && threadIdx.x < 16) msh[threadIdx.x] = 0u;
}

// ---------------- mean-shift partial pass: 2 i-rows/lane, uniform-j broadcast ----------------
// grid 512 = 16 i-tiles(512 rows) x 32 j-splits(256 j). block 256 = 4 waves.
__global__ __launch_bounds__(256, 2) void k_ms2(const float* __restrict__ x,
                                                const float* __restrict__ nx,
                                                const float* __restrict__ c,
                                                const float* __restrict__ nc,
                                                const float* __restrict__ sigma_p,
                                                float* __restrict__ P) {
    int t = threadIdx.x;
    int wv = __builtin_amdgcn_readfirstlane(t >> 6);
    int lane = t & 63;
    int it = (int)blockIdx.x >> 5, js = (int)blockIdx.x & 31;
    int i0 = it * 512 + wv * 128 + lane;
    int i1 = i0 + 64;

    float sg = sigma_p[0];
    float ng2 = -LOG2E / (2.f * sg * sg);   // w = exp2(ng2 * sq)

    float xi0[DIM], xi1[DIM];
    {
        const float4* xr0 = (const float4*)(x + (size_t)i0 * DIM);
        const float4* xr1 = (const float4*)(x + (size_t)i1 * DIM);
#pragma unroll
        for (int q = 0; q < 8; ++q) {
            float4 a = xr0[q], b = xr1[q];
            xi0[4 * q] = a.x; xi0[4 * q + 1] = a.y; xi0[4 * q + 2] = a.z; xi0[4 * q + 3] = a.w;
            xi1[4 * q] = b.x; xi1[4 * q + 1] = b.y; xi1[4 * q + 2] = b.z; xi1[4 * q + 3] = b.w;
        }
    }
    float nx0 = nx[i0], nx1 = nx[i1];

    float acc0[DIM], acc1[DIM];
#pragma unroll
    for (int d = 0; d < DIM; ++d) { acc0[d] = 0.f; acc1[d] = 0.f; }
    float ws0 = 0.f, ws1 = 0.f;

    int jb = js * 256;
    const float* cb = c + (size_t)jb * DIM;
    const float* xb = x + (size_t)jb * DIM;
    const float* ncb = nc + jb;

    for (int jj = 0; jj < 256; ++jj) {
        float w0, w1;
        {
            const float4* cr = (const float4*)(cb + (size_t)jj * DIM);
            float4 C[8];
#pragma unroll
            for (int q = 0; q < 8; ++q) C[q] = cr[q];
            float ncj = ncb[jj];
            float a0 = 0.f, a1 = 0.f, a2 = 0.f, a3 = 0.f;
            float b0 = 0.f, b1 = 0.f, b2 = 0.f, b3 = 0.f;
#pragma unroll
            for (int q = 0; q < 8; ++q) {
                a0 = fmaf(xi0[4 * q + 0], C[q].x, a0);
                a1 = fmaf(xi0[4 * q + 1], C[q].y, a1);
                a2 = fmaf(xi0[4 * q + 2], C[q].z, a2);
                a3 = fmaf(xi0[4 * q + 3], C[q].w, a3);
                b0 = fmaf(xi1[4 * q + 0], C[q].x, b0);
                b1 = fmaf(xi1[4 * q + 1], C[q].y, b1);
                b2 = fmaf(xi1[4 * q + 2], C[q].z, b2);
                b3 = fmaf(xi1[4 * q + 3], C[q].w, b3);
            }
            float sq0 = fmaxf(fmaf(-2.f, (a0 + a1) + (a2 + a3), nx0 + ncj), 0.f);
            float sq1 = fmaxf(fmaf(-2.f, (b0 + b1) + (b2 + b3), nx1 + ncj), 0.f);
            w0 = __builtin_amdgcn_exp2f(ng2 * sq0);
            w1 = __builtin_amdgcn_exp2f(ng2 * sq1);
        }
        ws0 += w0; ws1 += w1;
        {
            const float4* xr2 = (const float4*)(xb + (size_t)jj * DIM);
            float4 X[8];
#pragma unroll
            for (int q = 0; q < 8; ++q) X[q] = xr2[q];
#pragma unroll
            for (int q = 0; q < 8; ++q) {
                acc0[4 * q + 0] = fmaf(w0, X[q].x, acc0[4 * q + 0]);
                acc0[4 * q + 1] = fmaf(w0, X[q].y, acc0[4 * q + 1]);
                acc0[4 * q + 2] = fmaf(w0, X[q].z, acc0[4 * q + 2]);
                acc0[4 * q + 3] = fmaf(w0, X[q].w, acc0[4 * q + 3]);
                acc1[4 * q + 0] = fmaf(w1, X[q].x, acc1[4 * q + 0]);
                acc1[4 * q + 1] = fmaf(w1, X[q].y, acc1[4 * q + 1]);
                acc1[4 * q + 2] = fmaf(w1, X[q].z, acc1[4 * q + 2]);
                acc1[4 * q + 3] = fmaf(w1, X[q].w, acc1[4 * q + 3]);
            }
        }
    }

    size_t base = ((size_t)js * 33) * NPTS + i0;
#pragma unroll
    for (int d = 0; d < DIM; ++d) {
        P[base + (size_t)d * NPTS] = acc0[d];
        P[base + (size_t)d * NPTS + 64] = acc1[d];
    }
    P[base + (size_t)32 * NPTS] = ws0;
    P[base + (size_t)32 * NPTS + 64] = ws1;
}

// ---------------- reduce partials -> c_new, maxshift ----------------
__global__ __launch_bounds__(256) void k_reduce(const float* __restrict__ P,
                                                const float* __restrict__ c_cur,
                                                float* __restrict__ c_new,
                                                unsigned int* __restrict__ maxshift) {
    int i = blockIdx.x * 256 + threadIdx.x;
    float tot[33];
#pragma unroll
    for (int d = 0; d < 33; ++d) tot[d] = 0.f;
    for (int js = 0; js < 32; ++js) {
        size_t base = ((size_t)js * 33) * NPTS + i;
#pragma unroll
        for (int d = 0; d < 33; ++d) tot[d] += P[base + (size_t)d * NPTS];
    }
    float ws = tot[32];
    float inv = __builtin_amdgcn_rcpf(ws);
    inv = inv * (2.f - ws * inv);  // one NR step
    const float* co = c_cur + (size_t)i * DIM;
    float sh2 = 0.f;
    float ncv[DIM];
#pragma unroll
    for (int d = 0; d < DIM; ++d) {
        float v = tot[d] * inv;
        ncv[d] = v;
        float df = v - co[d];
        sh2 = fmaf(df, df, sh2);
    }
    float4* dst = (float4*)(c_new + (size_t)i * DIM);
#pragma unroll
    for (int q = 0; q < 8; ++q)
        dst[q] = make_float4(ncv[4 * q], ncv[4 * q + 1], ncv[4 * q + 2], ncv[4 * q + 3]);
    atomicMax(maxshift, __float_as_uint(__builtin_amdgcn_sqrtf(sh2)));
}

// ---------------- damped update + nc refresh (skipped when converged) ----------------
__global__ __launch_bounds__(256) void k_update(float* __restrict__ c_cur,
                                                const float* __restrict__ c_new,
                                                float* __restrict__ nc,
                                                const unsigned int* __restrict__ maxshift) {
    if (__uint_as_float(*maxshift) < TOL) return;
    int i = blockIdx.x * 256 + threadIdx.x;
    float4* cc = (float4*)(c_cur + (size_t)i * DIM);
    const float4* cn = (const float4*)(c_new + (size_t)i * DIM);
    float s = 0.f;
#pragma unroll
    for (int q = 0; q < 8; ++q) {
        float4 a = cc[q], b = cn[q];
        float4 r = make_float4(DAMP * a.x + (1.f - DAMP) * b.x,
                               DAMP * a.y + (1.f - DAMP) * b.y,
                               DAMP * a.z + (1.f - DAMP) * b.z,
                               DAMP * a.w + (1.f - DAMP) * b.w);
        cc[q] = r;
        s += r.x * r.x + r.y * r.y + r.z * r.z + r.w * r.w;
    }
    nc[i] = s;
}

// ---------------- scores: 2-row partial argmin per (p, j-split) ----------------
__global__ __launch_bounds__(256, 2) void k_scores2(const float* __restrict__ x,
                                                    const float* __restrict__ nx,
                                                    const float* __restrict__ c,
                                                    const float* __restrict__ nc,
                                                    float* __restrict__ pv,
                                                    int* __restrict__ pj) {
    int t = threadIdx.x;
    int wv = __builtin_amdgcn_readfirstlane(t >> 6);
    int lane = t & 63;
    int it = (int)blockIdx.x >> 5, js = (int)blockIdx.x & 31;
    int p0 = it * 512 + wv * 128 + lane;
    int p1 = p0 + 64;

    float xi0[DIM], xi1[DIM];
    {
        const float4* xr0 = (const float4*)(x + (size_t)p0 * DIM);
        const float4* xr1 = (const float4*)(x + (size_t)p1 * DIM);
#pragma unroll
        for (int q = 0; q < 8; ++q) {
            float4 a = xr0[q], b = xr1[q];
            xi0[4 * q] = a.x; xi0[4 * q + 1] = a.y; xi0[4 * q + 2] = a.z; xi0[4 * q + 3] = a.w;
            xi1[4 * q] = b.x; xi1[4 * q + 1] = b.y; xi1[4 * q + 2] = b.z; xi1[4 * q + 3] = b.w;
        }
    }
    float nxp0 = nx[p0], nxp1 = nx[p1];

    int jb = js * 256;
    const float* cb = c + (size_t)jb * DIM;
    const float* ncb = nc + jb;
    float bv0 = INFINITY, bv1 = INFINITY;
    int bj0 = jb, bj1 = jb;
    for (int jj = 0; jj < 256; ++jj) {
        const float4* cr = (const float4*)(cb + (size_t)jj * DIM);
        float4 C[8];
#pragma unroll
        for (int q = 0; q < 8; ++q) C[q] = cr[q];
        float ncj = ncb[jj];
        float a0 = 0.f, a1 = 0.f, a2 = 0.f, a3 = 0.f;
        float b0 = 0.f, b1 = 0.f, b2 = 0.f, b3 = 0.f;
#pragma unroll
        for (int q = 0; q < 8; ++q) {
            a0 = fmaf(xi0[4 * q + 0], C[q].x, a0);
            a1 = fmaf(xi0[4 * q + 1], C[q].y, a1);
            a2 = fmaf(xi0[4 * q + 2], C[q].z, a2);
            a3 = fmaf(xi0[4 * q + 3], C[q].w, a3);
            b0 = fmaf(xi1[4 * q + 0], C[q].x, b0);
            b1 = fmaf(xi1[4 * q + 1], C[q].y, b1);
            b2 = fmaf(xi1[4 * q + 2], C[q].z, b2);
            b3 = fmaf(xi1[4 * q + 3], C[q].w, b3);
        }
        float sq0 = fmaxf(fmaf(-2.f, (a0 + a1) + (a2 + a3), nxp0 + ncj), 0.f);
        float sq1 = fmaxf(fmaf(-2.f, (b0 + b1) + (b2 + b3), nxp1 + ncj), 0.f);
        if (sq0 < bv0) { bv0 = sq0; bj0 = jb + jj; }   // strict <: first min wins
        if (sq1 < bv1) { bv1 = sq1; bj1 = jb + jj; }
    }
    pv[(size_t)js * NPTS + p0] = bv0;
    pj[(size_t)js * NPTS + p0] = bj0;
    pv[(size_t)js * NPTS + p1] = bv1;
    pj[(size_t)js * NPTS + p1] = bj1;
}

__global__ __launch_bounds__(256) void k_score_comb(const float* __restrict__ pv,
                                                    const int* __restrict__ pj,
                                                    int* __restrict__ scores) {
    int p = blockIdx.x * 256 + threadIdx.x;
    float bv = pv[p];
    int bj = pj[p];
    for (int js = 1; js < 32; ++js) {
        float v = pv[(size_t)js * NPTS + p];
        int j = pj[(size_t)js * NPTS + p];
        if (v < bv) { bv = v; bj = j; }  // ascending js: first global min
    }
    atomicAdd(&scores[bj], 1);
}

// ---------------- stable descending rank (split + combine) ----------------
__global__ __launch_bounds__(256) void k_rank_part(const int* __restrict__ scores,
                                                   int* __restrict__ rkp) {
    int t = threadIdx.x;
    int wv = __builtin_amdgcn_readfirstlane(t >> 6);
    int lane = t & 63;
    int it = (int)blockIdx.x >> 5, js = (int)blockIdx.x & 31;
    int p = it * 256 + wv * 64 + lane;
    int sp = scores[p];
    int j0 = js * 256;
    int r = 0;
    for (int jj = 0; jj < 256; ++jj) {
        int sj = scores[j0 + jj];
        int j = j0 + jj;
        r += (sj > sp) || (sj == sp && j < p);
    }
    rkp[(size_t)js * NPTS + p] = r;
}

__global__ __launch_bounds__(256) void k_rank_comb(const int* __restrict__ rkp,
                                                   int* __restrict__ order) {
    int p = blockIdx.x * 256 + threadIdx.x;
    int r = 0;
    for (int js = 0; js < 32; ++js) r += rkp[(size_t)js * NPTS + p];
    order[r] = p;
}

// ---------------- greedy NMS scan (single block, ballot fast-forward) ----------------
__global__ __launch_bounds__(1024) void k_nms(const float* __restrict__ c,
                                              const int* __restrict__ order,
                                              const int* __restrict__ scores,
                                              const float* __restrict__ sigma_p,
                                              float* __restrict__ keep_out) {
    __shared__ int s_ord[NPTS];
    __shared__ unsigned char kp[NPTS];
    __shared__ int s_first[16];
    __shared__ int s_next;
    int t = threadIdx.x;
    for (int q = t; q < NPTS; q += 1024) { s_ord[q] = order[q]; kp[q] = 1; }
    __syncthreads();
    float sg = sigma_p[0];
    float thr2 = sg * sg;

    int k = 0;
    while (k < NPTS) {
        int cand = k + t;
        bool hit = (cand < NPTS) && (kp[s_ord[cand]] != 0);
        unsigned long long b = __ballot(hit);
        int wave = t >> 6;
        if ((t & 63) == 0)
            s_first[wave] = b ? (k + (wave << 6) + (__ffsll((unsigned long long)b) - 1))
                              : 0x7fffffff;
        __syncthreads();
        if (t == 0) {
            int mn = s_first[0];
            for (int w2 = 1; w2 < 16; ++w2) mn = min(mn, s_first[w2]);
            s_next = mn;
        }
        __syncthreads();
        int kf = s_next;
        if (kf == 0x7fffffff) { k += 1024; continue; }

        int idx = s_ord[kf];
        float ci[DIM];
        const float4* cr = (const float4*)(c + (size_t)idx * DIM);
#pragma unroll
        for (int q = 0; q < 8; ++q) {
            float4 v = cr[q];
            ci[4 * q] = v.x; ci[4 * q + 1] = v.y; ci[4 * q + 2] = v.z; ci[4 * q + 3] = v.w;
        }
#pragma unroll
        for (int m2 = 0; m2 < 8; ++m2) {
            int j = t + m2 * 1024;
            const float4* cj = (const float4*)(c + (size_t)j * DIM);
            float sq = 0.f;
#pragma unroll
            for (int q = 0; q < 8; ++q) {
                float4 v = cj[q];
                float e0 = v.x - ci[4 * q], e1 = v.y - ci[4 * q + 1];
                float e2 = v.z - ci[4 * q + 2], e3 = v.w - ci[4 * q + 3];
                sq += e0 * e0 + e1 * e1 + e2 * e2 + e3 * e3;
            }
            if (j != idx && sq < thr2) kp[j] = 0;
        }
        __syncthreads();
        if (t == 0) kp[idx] = (scores[idx] > 0) ? 1 : 0;
        __syncthreads();
        k = kf + 1;
    }
    __syncthreads();
    for (int q = t; q < NPTS; q += 1024) keep_out[q] = kp[q] ? 1.0f : 0.0f;
}

// ---------------- assignment pass 1: 2-row partial sum of exp(cost) (M == 0) ----------------
__global__ __launch_bounds__(256, 2) void k_apass1(const float* __restrict__ x,
                                                   const float* __restrict__ nx,
                                                   const float* __restrict__ c,
                                                   const float* __restrict__ nc,
                                                   const float* __restrict__ keepf,
                                                   float* __restrict__ ps) {
    int t = threadIdx.x;
    int wv = __builtin_amdgcn_readfirstlane(t >> 6);
    int lane = t & 63;
    int it = (int)blockIdx.x >> 5, js = (int)blockIdx.x & 31;
    int p0 = it * 512 + wv * 128 + lane;
    int p1 = p0 + 64;

    float xi0[DIM], xi1[DIM];
    {
        const float4* xr0 = (const float4*)(x + (size_t)p0 * DIM);
        const float4* xr1 = (const float4*)(x + (size_t)p1 * DIM);
#pragma unroll
        for (int q = 0; q < 8; ++q) {
            float4 a = xr0[q], b = xr1[q];
            xi0[4 * q] = a.x; xi0[4 * q + 1] = a.y; xi0[4 * q + 2] = a.z; xi0[4 * q + 3] = a.w;
            xi1[4 * q] = b.x; xi1[4 * q + 1] = b.y; xi1[4 * q + 2] = b.z; xi1[4 * q + 3] = b.w;
        }
    }
    float nxp0 = nx[p0], nxp1 = nx[p1];

    int jb = js * 256;
    const float* cb = c + (size_t)jb * DIM;
    const float* ncb = nc + jb;
    const float* kb = keepf + jb;
    float S0 = 0.f, S1 = 0.f;
    for (int jj = 0; jj < 256; ++jj) {
        const float4* cr = (const float4*)(cb + (size_t)jj * DIM);
        float4 C[8];
#pragma unroll
        for (int q = 0; q < 8; ++q) C[q] = cr[q];
        float ncj = ncb[jj];
        float kadd = (kb[jj] > 0.5f) ? 0.f : -1e38f;
        float a0 = 0.f, a1 = 0.f, a2 = 0.f, a3 = 0.f;
        float b0 = 0.f, b1 = 0.f, b2 = 0.f, b3 = 0.f;
#pragma unroll
        for (int q = 0; q < 8; ++q) {
            a0 = fmaf(xi0[4 * q + 0], C[q].x, a0);
            a1 = fmaf(xi0[4 * q + 1], C[q].y, a1);
            a2 = fmaf(xi0[4 * q + 2], C[q].z, a2);
            a3 = fmaf(xi0[4 * q + 3], C[q].w, a3);
            b0 = fmaf(xi1[4 * q + 0], C[q].x, b0);
            b1 = fmaf(xi1[4 * q + 1], C[q].y, b1);
            b2 = fmaf(xi1[4 * q + 2], C[q].z, b2);
            b3 = fmaf(xi1[4 * q + 3], C[q].w, b3);
        }
        float sq0 = fmaxf(fmaf(-2.f, (a0 + a1) + (a2 + a3), nxp0 + ncj), 0.f);
        float sq1 = fmaxf(fmaf(-2.f, (b0 + b1) + (b2 + b3), nxp1 + ncj), 0.f);
        float r0 = __builtin_amdgcn_sqrtf(sq0 + 1e-12f);
        float r1 = __builtin_amdgcn_sqrtf(sq1 + 1e-12f);
        S0 += __builtin_amdgcn_exp2f(fmaf(r0, -LOG2E, kadd));
        S1 += __builtin_amdgcn_exp2f(fmaf(r1, -LOG2E, kadd));
    }
    ps[(size_t)js * NPTS + p0] = S0;
    ps[(size_t)js * NPTS + p1] = S1;
}

// ---------------- assignment pass 2: lane owns j, x-tile broadcast from LDS ----------------
// grid 2048 = 64 p-tiles(128) x 32 j-tiles(256). block 256 = 4 waves x 64 j.
__global__ __launch_bounds__(256, 4) void k_apass2(const float* __restrict__ x,
                                                   const float* __restrict__ c,
                                                   const float* __restrict__ keepf,
                                                   const float* __restrict__ ps,
                                                   float* __restrict__ A) {
    __shared__ float sx[128 * 36];   // row stride 36 floats (16B aligned)
    __shared__ float snx[128];
    __shared__ float sscale[128];
    __shared__ float spart[256];
    int t = threadIdx.x;
    int wv = __builtin_amdgcn_readfirstlane(t >> 6);
    int lane = t & 63;
    int pt = (int)blockIdx.x >> 5, jt = (int)blockIdx.x & 31;
    int p0 = pt * 128, j0 = jt * 256;

    {   // stage x-tile: thread t handles floats [t*16, t*16+16)
        const float4* src = (const float4*)(x + (size_t)p0 * DIM) + t * 4;
        int row = t >> 1, colh = (t & 1) * 16;
        float4* dst = (float4*)(sx + row * 36 + colh);
        float s = 0.f;
#pragma unroll
        for (int q = 0; q < 4; ++q) {
            float4 v = src[q];
            dst[q] = v;
            s += v.x * v.x + v.y * v.y + v.z * v.z + v.w * v.w;
        }
        spart[t] = s;
    }
    __syncthreads();
    if (t < 128) {
        snx[t] = spart[2 * t] + spart[2 * t + 1];
        float SS = 0.f;
        for (int js = 0; js < 32; ++js) SS += ps[(size_t)js * NPTS + p0 + t];
        sscale[t] = 1.f / SS;
    }

    int j = j0 + wv * 64 + lane;
    float cj[DIM];
    float ncj = 0.f;
    {
        const float4* cr = (const float4*)(c + (size_t)j * DIM);
#pragma unroll
        for (int q = 0; q < 8; ++q) {
            float4 v = cr[q];
            cj[4 * q] = v.x; cj[4 * q + 1] = v.y; cj[4 * q + 2] = v.z; cj[4 * q + 3] = v.w;
            ncj += v.x * v.x + v.y * v.y + v.z * v.z + v.w * v.w;
        }
    }
    float kadd = (keepf[j] > 0.5f) ? 0.f : -1e38f;
    __syncthreads();

    for (int pp = 0; pp < 128; ++pp) {
        const float4* xs = (const float4*)(sx + pp * 36);
        float d0 = 0.f, d1 = 0.f, d2 = 0.f, d3 = 0.f;
#pragma unroll
        for (int q = 0; q < 8; ++q) {
            float4 v = xs[q];
            d0 = fmaf(cj[4 * q + 0], v.x, d0);
            d1 = fmaf(cj[4 * q + 1], v.y, d1);
            d2 = fmaf(cj[4 * q + 2], v.z, d2);
            d3 = fmaf(cj[4 * q + 3], v.w, d3);
        }
        float sq = fmaxf(fmaf(-2.f, (d0 + d1) + (d2 + d3), snx[pp] + ncj), 0.f);
        float rt = __builtin_amdgcn_sqrtf(sq + 1e-12f);
        float tt = fmaf(rt, -LOG2E, kadd);
        A[(size_t)(p0 + pp) * NPTS + j] = __builtin_amdgcn_exp2f(tt) * sscale[pp];
    }
}

extern "C" void kernel_launch(void* const* d_in, const int* in_sizes, int n_in,
                              void* d_out, int out_size, void* d_ws, size_t ws_size,
                              hipStream_t stream) {
    const float* x = (const float*)d_in[0];
    const float* sigma = (const float*)d_in[1];

    float* out = (float*)d_out;
    float* OUT_C = out;                          // NPTS*DIM
    float* A = out + (size_t)NPTS * DIM;         // NPTS*NPTS
    float* OUT_K = A + (size_t)NPTS * NPTS;      // NPTS

    float* msP = A + OFF_MSP;
    float* c_cur = A + OFF_CCUR;
    float* c_new = A + OFF_CNEW;
    float* nx = A + OFF_NX;
    float* nc = A + OFF_NC;
    float* pv = A + OFF_PV;
    int* pj = (int*)(A + OFF_PJ);
    int* rkp = (int*)(A + OFF_RKP);
    unsigned int* msh = (unsigned int*)(A + OFF_MSH);
    int* scores = (int*)(A + OFF_SCO);
    int* order = (int*)(A + OFF_ORD);
    float* ps = (float*)d_ws;                    // 1 MB, survives apass2

    k_init<<<NPTS / 256, 256, 0, stream>>>(x, c_cur, nx, nc, scores, msh);
    for (int itr = 0; itr < MAX_ITER; ++itr) {
        k_ms2<<<512, 256, 0, stream>>>(x, nx, c_cur, nc, sigma, msP);
        k_reduce<<<NPTS / 256, 256, 0, stream>>>(msP, c_cur, c_new, msh + itr);
        k_update<<<NPTS / 256, 256, 0, stream>>>(c_cur, c_new, nc, msh + itr);
    }
    hipMemcpyAsync(OUT_C, c_cur, (size_t)NPTS * DIM * sizeof(float),
                   hipMemcpyDeviceToDevice, stream);

    k_scores2<<<512, 256, 0, stream>>>(x, nx, OUT_C, nc, pv, pj);
    k_score_comb<<<NPTS / 256, 256, 0, stream>>>(pv, pj, scores);
    k_rank_part<<<1024, 256, 0, stream>>>(scores, rkp);
    k_rank_comb<<<NPTS / 256, 256, 0, stream>>>(rkp, order);
    k_nms<<<1, 1024, 0, stream>>>(OUT_C, order, scores, sigma, OUT_K);

    k_apass1<<<512, 256, 0, stream>>>(x, nx, OUT_C, nc, OUT_K, ps);
    k_apass2<<<2048, 256, 0, stream>>>(x, OUT_C, OUT_K, ps, A);
}